// Round 11
// baseline (267.137 us; speedup 1.0000x reference)
//
#include <hip/hip_runtime.h>
#include <stdint.h>

#define HDIM 64
#define TDIM 512
#define GB   16   // batches per team (one MFMA N-tile)
#define NT   2    // independent teams per block

// ---- Dual-team MFMA RNN: 2 independent 16-batch groups per 8-wave block ----
// r10 (verified, 830 cy/step): 4 waves, 1 wave/SIMD -> each wave busy ~25%,
// stalled ~75% (barrier skew + lgkm drain + post-barrier LDS latency) with
// nothing to overlap. r5's fix attempt (2 blocks/CU) halved GB and doubled
// per-batch work. r11 keeps GB=16 and packs TWO complete independent groups
// into one 512-thread block: 128 blocks x 8 waves = 2 waves/SIMD, zero extra
// work. Teams share the block barrier (symmetric cadence); on each SIMD the
// A-wave's stall phases are covered by the B-wave's compute and vice versa.
// Everything else is r10 verbatim (absmax 0.001953), team-indexed:
//   transposed update S_new[64h x 16b] = tanh(xw + W'*S), state=B-operand,
//   phi(16w+4g+r) = 32*(w>>1)+8g+4*(w&1)+r on W_hh rows/W_ih/bias/fc_w,
//   f16 hi/lo 3-term product (f32 acc), K=2*log2(e) folded into W/bias,
//   bit-mask hi split + cvt_pkrtz pack, ping-pong state, ONE barrier/step.
// NOTE (r6 lesson): f16-only state would be ~100x cheaper per step but the
// recurrence amplifies per-step error ~10^3; hi/lo (~1e-6/step) -> 2e-3
// final. f16-only (~2.4e-4/step) would blow the 2.4e-2 threshold. Keep hi/lo.

typedef float    f32x4 __attribute__((ext_vector_type(4)));
typedef _Float16 f16x8 __attribute__((ext_vector_type(8)));
typedef unsigned int u32;
typedef unsigned int u32x2 __attribute__((ext_vector_type(2)));
typedef unsigned int u32x4 __attribute__((ext_vector_type(4)));

__device__ __forceinline__ u32 pk2(float a, float b) {
    return __builtin_bit_cast(u32, __builtin_amdgcn_cvt_pkrtz(a, b));
}
__device__ __forceinline__ float hi_mask(float v) {
    // top-13-mantissa-bit truncation: exactly f16-representable for |v|<=1
    return __builtin_bit_cast(float, __builtin_bit_cast(u32, v) & 0xFFFFE000u);
}

__global__ __launch_bounds__(512, 2)
void rnn_dualteam(const float* __restrict__ x,
                  const float* __restrict__ W_ih,
                  const float* __restrict__ W_hh,
                  const float* __restrict__ b_ih,
                  const float* __restrict__ b_hh,
                  const float* __restrict__ fc_w,
                  const float* __restrict__ fc_b,
                  float* __restrict__ out,
                  int B)
{
    // [team][pingpong][quad][lane][dword]; quads: 0=hi-c0 1=hi-c1 2=lo-c0 3=lo-c1
    __shared__ __align__(16) u32 st[NT][2][4][64][4];   // 16 KB
    __shared__ float xs[NT][64][GB];                    // 8 KB x chunks
    __shared__ float red[NT][4][GB];                    // final reduction

    const int tid  = threadIdx.x;               // block = 8 waves = 2 teams
    const int ttid = tid & 255;                 // tid within team
    const int team = tid >> 8;                  // 0,1
    const int lane = tid & 63;
    const int w    = (tid >> 6) & 3;            // wave role within team
    const int b    = lane & 15;                 // batch col (B/D col)
    const int g    = lane >> 4;                 // k-group / D row-group
    const int m16  = lane & 15;
    const int gb0  = blockIdx.x * (GB * NT) + team * GB;
    const int wc   = w >> 1;                    // chunk this wave feeds
    const int wh   = w & 1;                     // dword-pair within chunk

    const float K = 2.885390081777927f;         // 2*log2(e), folded into W & bias

    // ---- A-frags (tile w): rows phi(16w + m16), f16 hi/lo, K-scaled ----
    f16x8 Ahi0, Ahi1, Alo0, Alo1;               // chunk 0 / chunk 1
    {
        const int wr = 32*wc + 8*(m16 >> 2) + 4*wh + (m16 & 3);
        const float* wrow = W_hh + wr * HDIM;
        const f32x4 va0 = *(const f32x4*)(wrow + 8*g);
        const f32x4 vb0 = *(const f32x4*)(wrow + 8*g + 4);
        const f32x4 va1 = *(const f32x4*)(wrow + 32 + 8*g);
        const f32x4 vb1 = *(const f32x4*)(wrow + 32 + 8*g + 4);
#pragma unroll
        for (int e = 0; e < 4; ++e) {
            float v; _Float16 h;
            v = K*va0[e]; h = (_Float16)v; Ahi0[e]   = h; Alo0[e]   = (_Float16)(v - (float)h);
            v = K*vb0[e]; h = (_Float16)v; Ahi0[e+4] = h; Alo0[e+4] = (_Float16)(v - (float)h);
            v = K*va1[e]; h = (_Float16)v; Ahi1[e]   = h; Alo1[e]   = (_Float16)(v - (float)h);
            v = K*vb1[e]; h = (_Float16)v; Ahi1[e+4] = h; Alo1[e+4] = (_Float16)(v - (float)h);
        }
    }

    // ---- C-init constants: D reg r -> h-index 32wc + 8g + 4wh + r ----
    float wihc[4], biasc[4];
#pragma unroll
    for (int r = 0; r < 4; ++r) {
        const int idx = 32*wc + 8*g + 4*wh + r;
        wihc[r]  = K * W_ih[idx];
        biasc[r] = K * (b_ih[idx] + b_hh[idx]);
    }

    // zero both teams' ping-pong state buffers (16 KB): h(0)=0
    {
        const u32x4 z = {0u, 0u, 0u, 0u};
        ((u32x4*)st)[tid]       = z;            // 512 x 16B = 8 KB
        ((u32x4*)st)[tid + 512] = z;            // + 8 KB
    }

    const int sm = ttid >> 4;                   // x staging: batch row (team)
    const int tq = ttid & 15;                   // t-quad
    const f32x4 zero4 = {0.f, 0.f, 0.f, 0.f};

    float hv0 = 0.f, hv1 = 0.f, hv2 = 0.f, hv3 = 0.f;

#pragma unroll 1
    for (int tc = 0; tc < TDIM/64; ++tc) {
        const f32x4 xv4 = *(const f32x4*)(x + (size_t)(gb0 + sm) * TDIM
                                            + tc*64 + tq*4);
        xs[team][tq*4 + 0][sm] = xv4.x;
        xs[team][tq*4 + 1][sm] = xv4.y;
        xs[team][tq*4 + 2][sm] = xv4.z;
        xs[team][tq*4 + 3][sm] = xv4.w;
        __syncthreads();    // publish xs (and the zeroed st at tc==0)

#pragma unroll 1
        for (int tj = 0; tj < 64; ++tj) {
            const int pp = tj & 1;      // global parity: tc*64 is even
            // h(t) from read buffer (published by previous step's barrier)
            const f16x8 ih0 = __builtin_bit_cast(f16x8, *(const u32x4*)&st[team][pp][0][lane][0]);
            const f16x8 ih1 = __builtin_bit_cast(f16x8, *(const u32x4*)&st[team][pp][1][lane][0]);
            const f16x8 il0 = __builtin_bit_cast(f16x8, *(const u32x4*)&st[team][pp][2][lane][0]);
            const f16x8 il1 = __builtin_bit_cast(f16x8, *(const u32x4*)&st[team][pp][3][lane][0]);
            const float xt = xs[team][tj][b];

            f32x4 c1, c1b, c2, c2b, c3, c3b;
            c1.x = fmaf(xt, wihc[0], biasc[0]);
            c1.y = fmaf(xt, wihc[1], biasc[1]);
            c1.z = fmaf(xt, wihc[2], biasc[2]);
            c1.w = fmaf(xt, wihc[3], biasc[3]);
            c1b = zero4; c2 = zero4; c2b = zero4; c3 = zero4; c3b = zero4;

            // six independent depth-1 MFMAs (hi*hi + hi*lo + lo*hi, 2 chunks)
            c1  = __builtin_amdgcn_mfma_f32_16x16x32_f16(Ahi0, ih0, c1,  0, 0, 0);
            c1b = __builtin_amdgcn_mfma_f32_16x16x32_f16(Ahi1, ih1, c1b, 0, 0, 0);
            c2  = __builtin_amdgcn_mfma_f32_16x16x32_f16(Ahi0, il0, c2,  0, 0, 0);
            c2b = __builtin_amdgcn_mfma_f32_16x16x32_f16(Ahi1, il1, c2b, 0, 0, 0);
            c3  = __builtin_amdgcn_mfma_f32_16x16x32_f16(Alo0, ih0, c3,  0, 0, 0);
            c3b = __builtin_amdgcn_mfma_f32_16x16x32_f16(Alo1, ih1, c3b, 0, 0, 0);

            const f32x4 zsum = (c1 + c1b) + ((c2 + c2b) + (c3 + c3b));

            // tanh(z) = 1 - 2/(1 + e^{2z}); inputs already K-scaled
            hv0 = fmaf(-2.0f, __builtin_amdgcn_rcpf(__builtin_amdgcn_exp2f(zsum.x) + 1.0f), 1.0f);
            hv1 = fmaf(-2.0f, __builtin_amdgcn_rcpf(__builtin_amdgcn_exp2f(zsum.y) + 1.0f), 1.0f);
            hv2 = fmaf(-2.0f, __builtin_amdgcn_rcpf(__builtin_amdgcn_exp2f(zsum.z) + 1.0f), 1.0f);
            hv3 = fmaf(-2.0f, __builtin_amdgcn_rcpf(__builtin_amdgcn_exp2f(zsum.w) + 1.0f), 1.0f);

            const float h0 = hi_mask(hv0), h1 = hi_mask(hv1);
            const float h2 = hi_mask(hv2), h3 = hi_mask(hv3);
            u32x2 nh, nl;
            nh.x = pk2(h0, h1);           nh.y = pk2(h2, h3);
            nl.x = pk2(hv0-h0, hv1-h1);   nl.y = pk2(hv2-h2, hv3-h3);

            // write h(t+1) into the OTHER buffer; one barrier publishes it.
            // (WAR-safe: reads of st[pp^1] happened in step t-1, before its
            //  barrier.)
            *(u32x2*)&st[team][pp ^ 1][wc][lane][2*wh]     = nh;
            *(u32x2*)&st[team][pp ^ 1][2 + wc][lane][2*wh] = nl;
            __syncthreads();
        }
    }

    // ---- out[b] = sum_j h[j]*fc_w[j] + fc_b ----
    // Lane's 4 final h-values (exact f32): indices 32wc + 8g + 4wh + r.
    float acc = 0.0f;
    acc = fmaf(hv0, fc_w[32*wc + 8*g + 4*wh + 0], acc);
    acc = fmaf(hv1, fc_w[32*wc + 8*g + 4*wh + 1], acc);
    acc = fmaf(hv2, fc_w[32*wc + 8*g + 4*wh + 2], acc);
    acc = fmaf(hv3, fc_w[32*wc + 8*g + 4*wh + 3], acc);
    acc += __shfl_xor(acc, 16, 64);   // sum the 4 g-groups of this batch col
    acc += __shfl_xor(acc, 32, 64);
    if (lane < 16) red[team][w][lane] = acc;
    __syncthreads();
    if (ttid < GB)
        out[gb0 + ttid] = red[team][0][ttid] + red[team][1][ttid]
                        + red[team][2][ttid] + red[team][3][ttid] + fc_b[0];
}

extern "C" void kernel_launch(void* const* d_in, const int* in_sizes, int n_in,
                              void* d_out, int out_size, void* d_ws, size_t ws_size,
                              hipStream_t stream)
{
    const float* x    = (const float*)d_in[0];
    const float* W_ih = (const float*)d_in[1];
    const float* W_hh = (const float*)d_in[2];
    const float* b_ih = (const float*)d_in[3];
    const float* b_hh = (const float*)d_in[4];
    const float* fc_w = (const float*)d_in[5];
    const float* fc_b = (const float*)d_in[6];
    float* out = (float*)d_out;

    const int B = in_sizes[0] / TDIM;      // x is (B, T, 1), B = 4096
    const int blocks = B / (GB * NT);      // 128 blocks x 8 waves = full chip
                                           // at 2 waves/SIMD

    rnn_dualteam<<<blocks, 512, 0, stream>>>(
        x, W_ih, W_hh, b_ih, b_hh, fc_w, fc_b, out, B);
}

// Round 12
// 207.618 us; speedup vs baseline: 1.2867x; 1.2867x over previous
//
#include <hip/hip_runtime.h>
#include <stdint.h>

#define HDIM 64
#define TDIM 512
#define GB   16   // batches per block (one MFMA N-tile)

// ---- 4-wave MFMA RNN, ping-pong state, 1 barrier/step, slim inner loop ----
// r10 (verified 830 cy/step, 177 us) + three instruction-level cuts found by
// counter accounting (VALUBusy 42% => ~175 instr/step vs ~95 real):
//   1. Step loop unrolled x2 with COMPILE-TIME parity: all LDS state
//      addresses = one hoisted base + ds 16-bit immediate (pp*4096+q*1024);
//      r10's runtime pp=tj&1 recomputed addresses every step.
//   2. 3 chains of 2-deep MFMA (was 6 flat accumulators): zero-init movs
//      20->8, zsum adds 20->8, for ~1 extra MFMA-dep latency.
//   3. x_t prefetched one step ahead into a register: xs is constant within
//      a chunk, so the read is barrier-independent -> off the critical chain.
// Protocol/mapping/numerics byte-identical to r10:
//   transposed update S_new[64h x 16b] = tanh(xw + W'*S), state=B-operand,
//   phi(16w+4g+r) = 32*(w>>1)+8g+4*(w&1)+r on W_hh rows/W_ih/bias/fc_w,
//   f16 hi/lo 3-term product (f32 acc), K=2*log2(e) folded into W/bias,
//   bit-mask hi split + cvt_pkrtz pack, ping-pong state, ONE barrier/step.
// Geometry note (r11 lesson): B=4096, GB=16 => 256 groups; full-chip needs
// >=256 blocks, so 4 waves/block at 1 wave/SIMD is the only non-duplicating
// full-chip packing. 8-wave/128-block variants idle half the CUs (r11:
// occupancy 11.5%, 217 us).

typedef float    f32x4 __attribute__((ext_vector_type(4)));
typedef _Float16 f16x8 __attribute__((ext_vector_type(8)));
typedef unsigned int u32;
typedef unsigned int u32x2 __attribute__((ext_vector_type(2)));
typedef unsigned int u32x4 __attribute__((ext_vector_type(4)));

__device__ __forceinline__ u32 pk2(float a, float b) {
    return __builtin_bit_cast(u32, __builtin_amdgcn_cvt_pkrtz(a, b));
}
__device__ __forceinline__ float hi_mask(float v) {
    // top-13-mantissa-bit truncation: exactly f16-representable for |v|<=1
    return __builtin_bit_cast(float, __builtin_bit_cast(u32, v) & 0xFFFFE000u);
}

__global__ __launch_bounds__(256, 1)
__attribute__((amdgpu_waves_per_eu(1)))
void rnn_pp_slim(const float* __restrict__ x,
                 const float* __restrict__ W_ih,
                 const float* __restrict__ W_hh,
                 const float* __restrict__ b_ih,
                 const float* __restrict__ b_hh,
                 const float* __restrict__ fc_w,
                 const float* __restrict__ fc_b,
                 float* __restrict__ out,
                 int B)
{
    // [pingpong][quad][lane][dword]; quads: 0=hi-c0 1=hi-c1 2=lo-c0 3=lo-c1
    __shared__ __align__(16) u32 st[2][4][64][4];   // 8 KB
    __shared__ float xs[66][GB];                    // x chunk [t][b] (+2 pad)
    __shared__ float red[4][GB];                    // final reduction

    const int tid  = threadIdx.x;               // block = 4 waves
    const int lane = tid & 63;
    const int w    = tid >> 6;                  // wave id = output tile
    const int b    = lane & 15;                 // batch col (B/D col)
    const int g    = lane >> 4;                 // k-group / D row-group
    const int m16  = lane & 15;
    const int gb0  = blockIdx.x * GB;
    const int wc   = w >> 1;                    // chunk this wave feeds
    const int wh   = w & 1;                     // dword-pair within chunk

    const float K = 2.885390081777927f;         // 2*log2(e), folded into W & bias

    // ---- A-frags (tile w): rows phi(16w + m16), f16 hi/lo, K-scaled ----
    f16x8 Ahi0, Ahi1, Alo0, Alo1;               // chunk 0 / chunk 1
    {
        const int wr = 32*wc + 8*(m16 >> 2) + 4*wh + (m16 & 3);
        const float* wrow = W_hh + wr * HDIM;
        const f32x4 va0 = *(const f32x4*)(wrow + 8*g);
        const f32x4 vb0 = *(const f32x4*)(wrow + 8*g + 4);
        const f32x4 va1 = *(const f32x4*)(wrow + 32 + 8*g);
        const f32x4 vb1 = *(const f32x4*)(wrow + 32 + 8*g + 4);
#pragma unroll
        for (int e = 0; e < 4; ++e) {
            float v; _Float16 h;
            v = K*va0[e]; h = (_Float16)v; Ahi0[e]   = h; Alo0[e]   = (_Float16)(v - (float)h);
            v = K*vb0[e]; h = (_Float16)v; Ahi0[e+4] = h; Alo0[e+4] = (_Float16)(v - (float)h);
            v = K*va1[e]; h = (_Float16)v; Ahi1[e]   = h; Alo1[e]   = (_Float16)(v - (float)h);
            v = K*vb1[e]; h = (_Float16)v; Ahi1[e+4] = h; Alo1[e+4] = (_Float16)(v - (float)h);
        }
    }

    // ---- C-init constants: D reg r -> h-index 32wc + 8g + 4wh + r ----
    float wihc[4], biasc[4];
#pragma unroll
    for (int r = 0; r < 4; ++r) {
        const int idx = 32*wc + 8*g + 4*wh + r;
        wihc[r]  = K * W_ih[idx];
        biasc[r] = K * (b_ih[idx] + b_hh[idx]);
    }

    // zero both ping-pong state buffers (8 KB): h(0)=0
    {
        const u32x4 z = {0u, 0u, 0u, 0u};
        ((u32x4*)st)[tid]       = z;
        ((u32x4*)st)[tid + 256] = z;
    }

    const int sm = tid >> 4;                    // x staging: batch row
    const int tq = tid & 15;                    // t-quad
    const f32x4 zero4 = {0.f, 0.f, 0.f, 0.f};

    float hv0 = 0.f, hv1 = 0.f, hv2 = 0.f, hv3 = 0.f;

    // One timestep, compile-time parity PP. XT = this step's x (register,
    // prefetched); XN = next step's x, loaded early (off-chain). All state
    // LDS addresses are base + immediate (PP, quad compile-time).
#define STEP(PP, XT, XN, TNEXT)                                               \
    {                                                                         \
        const f16x8 ih0 = __builtin_bit_cast(f16x8, *(const u32x4*)&st[PP][0][lane][0]); \
        const f16x8 ih1 = __builtin_bit_cast(f16x8, *(const u32x4*)&st[PP][1][lane][0]); \
        const f16x8 il0 = __builtin_bit_cast(f16x8, *(const u32x4*)&st[PP][2][lane][0]); \
        const f16x8 il1 = __builtin_bit_cast(f16x8, *(const u32x4*)&st[PP][3][lane][0]); \
        XN = xs[(TNEXT)][b];                       /* off-chain prefetch */   \
        f32x4 c1, c2, c3;                                                     \
        c1.x = fmaf(XT, wihc[0], biasc[0]);                                   \
        c1.y = fmaf(XT, wihc[1], biasc[1]);                                   \
        c1.z = fmaf(XT, wihc[2], biasc[2]);                                   \
        c1.w = fmaf(XT, wihc[3], biasc[3]);                                   \
        c2 = zero4; c3 = zero4;                                               \
        /* 3 chains x 2-deep: hi*hi | hi*lo | lo*hi, chunks 0+1 */            \
        c1 = __builtin_amdgcn_mfma_f32_16x16x32_f16(Ahi0, ih0, c1, 0, 0, 0);  \
        c2 = __builtin_amdgcn_mfma_f32_16x16x32_f16(Ahi0, il0, c2, 0, 0, 0);  \
        c3 = __builtin_amdgcn_mfma_f32_16x16x32_f16(Alo0, ih0, c3, 0, 0, 0);  \
        c1 = __builtin_amdgcn_mfma_f32_16x16x32_f16(Ahi1, ih1, c1, 0, 0, 0);  \
        c2 = __builtin_amdgcn_mfma_f32_16x16x32_f16(Ahi1, il1, c2, 0, 0, 0);  \
        c3 = __builtin_amdgcn_mfma_f32_16x16x32_f16(Alo1, ih1, c3, 0, 0, 0);  \
        const f32x4 zsum = c1 + (c2 + c3);                                    \
        /* tanh(z) = 1 - 2/(1 + e^{2z}); inputs already K-scaled */           \
        hv0 = fmaf(-2.0f, __builtin_amdgcn_rcpf(__builtin_amdgcn_exp2f(zsum.x) + 1.0f), 1.0f); \
        hv1 = fmaf(-2.0f, __builtin_amdgcn_rcpf(__builtin_amdgcn_exp2f(zsum.y) + 1.0f), 1.0f); \
        hv2 = fmaf(-2.0f, __builtin_amdgcn_rcpf(__builtin_amdgcn_exp2f(zsum.z) + 1.0f), 1.0f); \
        hv3 = fmaf(-2.0f, __builtin_amdgcn_rcpf(__builtin_amdgcn_exp2f(zsum.w) + 1.0f), 1.0f); \
        const float h0 = hi_mask(hv0), h1 = hi_mask(hv1);                     \
        const float h2 = hi_mask(hv2), h3 = hi_mask(hv3);                     \
        u32x2 nh, nl;                                                         \
        nh.x = pk2(h0, h1);           nh.y = pk2(h2, h3);                     \
        nl.x = pk2(hv0-h0, hv1-h1);   nl.y = pk2(hv2-h2, hv3-h3);             \
        /* write h(t+1) into the other buffer; barrier publishes it.   */     \
        /* (WAR-safe: reads of st[PP^1] were in step t-1, before its   */     \
        /*  barrier.)                                                  */     \
        *(u32x2*)&st[(PP) ^ 1][wc][lane][2*wh]     = nh;                      \
        *(u32x2*)&st[(PP) ^ 1][2 + wc][lane][2*wh] = nl;                      \
        __syncthreads();                                                      \
    }

#pragma unroll 1
    for (int tc = 0; tc < TDIM/64; ++tc) {
        const f32x4 xv4 = *(const f32x4*)(x + (size_t)(gb0 + sm) * TDIM
                                            + tc*64 + tq*4);
        xs[tq*4 + 0][sm] = xv4.x;
        xs[tq*4 + 1][sm] = xv4.y;
        xs[tq*4 + 2][sm] = xv4.z;
        xs[tq*4 + 3][sm] = xv4.w;
        __syncthreads();    // publish xs (and the zeroed st at tc==0)

        float xt = xs[0][b], xn;
#pragma unroll 1
        for (int tj = 0; tj < 64; tj += 2) {
            // global parity: tc*64 is even, so step tj has parity tj&1
            STEP(0, xt, xn, tj + 1)     // reads st[0], writes st[1]
            STEP(1, xn, xt, tj + 2)     // reads st[1], writes st[0]
            // (tj=62: reads xs[64] -> pad row, value discarded next chunk)
        }
    }
#undef STEP

    // ---- out[b] = sum_j h[j]*fc_w[j] + fc_b ----
    // Lane's 4 final h-values (exact f32): indices 32wc + 8g + 4wh + r.
    float acc = 0.0f;
    acc = fmaf(hv0, fc_w[32*wc + 8*g + 4*wh + 0], acc);
    acc = fmaf(hv1, fc_w[32*wc + 8*g + 4*wh + 1], acc);
    acc = fmaf(hv2, fc_w[32*wc + 8*g + 4*wh + 2], acc);
    acc = fmaf(hv3, fc_w[32*wc + 8*g + 4*wh + 3], acc);
    acc += __shfl_xor(acc, 16, 64);   // sum the 4 g-groups of this batch col
    acc += __shfl_xor(acc, 32, 64);
    if (lane < 16) red[w][lane] = acc;
    __syncthreads();
    if (tid < GB)
        out[gb0 + tid] = red[0][tid] + red[1][tid] + red[2][tid] + red[3][tid]
                       + fc_b[0];
}

extern "C" void kernel_launch(void* const* d_in, const int* in_sizes, int n_in,
                              void* d_out, int out_size, void* d_ws, size_t ws_size,
                              hipStream_t stream)
{
    const float* x    = (const float*)d_in[0];
    const float* W_ih = (const float*)d_in[1];
    const float* W_hh = (const float*)d_in[2];
    const float* b_ih = (const float*)d_in[3];
    const float* b_hh = (const float*)d_in[4];
    const float* fc_w = (const float*)d_in[5];
    const float* fc_b = (const float*)d_in[6];
    float* out = (float*)d_out;

    const int B = in_sizes[0] / TDIM;      // x is (B, T, 1)
    const int blocks = B / GB;             // 256 blocks x 4 waves = full chip

    rnn_pp_slim<<<blocks, 256, 0, stream>>>(
        x, W_ih, W_hh, b_ih, b_hh, fc_w, fc_b, out, B);
}